// Round 1
// baseline (735.766 us; speedup 1.0000x reference)
//
#include <hip/hip_runtime.h>

// ---------------------------------------------------------------------------
// Fused sparse-attention:  per-head QKV (MFMA) -> elementwise softmax(q*k)*v
// -> unifyheads GEMM (MFMA), single pass over x, single write of result.
// N=131072, e=512, h=8, s=64.  All matmuls bf16 MFMA 16x16x32, fp32 accum.
// ---------------------------------------------------------------------------

typedef __bf16 bf16x8 __attribute__((ext_vector_type(8)));
typedef float  f32x4  __attribute__((ext_vector_type(4)));

#define MFMA16(A, B, C) __builtin_amdgcn_mfma_f32_16x16x32_bf16((A), (B), (C), 0, 0, 0)

#define NPTS  131072
#define BN    128           // rows per block
#define LDW   88            // LDS leading dim (bf16): 176 B rows -> 16B-aligned, ~2-way banks
#define QKSCALE 0.044194173824159216f   // 1/sqrt(512)

// ---------------- weight prep: fp32 -> bf16, transposed/packed -------------
// wu_p  [h][j=512][kk=64]  = Wu[h*64+kk][j]          (B-frag: 8 contiguous k)
// wqkv_t[h][row=192][s=64] : row 0..63 = Wq^T[t][s], 64..127 = Wk^T, 128..191 = Wv^T
__global__ void prep_weights(const float* __restrict__ Wq, const float* __restrict__ Wk,
                             const float* __restrict__ Wv, const float* __restrict__ Wu,
                             __bf16* __restrict__ wu_p, __bf16* __restrict__ wqkv_t)
{
    int idx = blockIdx.x * 512 + threadIdx.x;
    if (idx < 512 * 512) {
        int kk = idx & 63;
        int j  = (idx >> 6) & 511;
        int h  = idx >> 15;
        wu_p[idx] = (__bf16)Wu[(h * 64 + kk) * 512 + j];
    } else {
        int o = idx - 512 * 512;
        if (o < 8 * 192 * 64) {
            int s    = o & 63;
            int row  = (o >> 6) % 192;
            int h    = (o >> 6) / 192;
            int type = row >> 6;          // 0=q,1=k,2=v
            int t    = row & 63;
            const float* W = (type == 0) ? Wq : (type == 1) ? Wk : Wv;
            wqkv_t[o] = (__bf16)W[h * 4096 + s * 64 + t];
        }
    }
}

__device__ __forceinline__ bf16x8 cvt8(float4 a, float4 b)
{
    bf16x8 r;
    r[0] = (__bf16)a.x; r[1] = (__bf16)a.y; r[2] = (__bf16)a.z; r[3] = (__bf16)a.w;
    r[4] = (__bf16)b.x; r[5] = (__bf16)b.y; r[6] = (__bf16)b.z; r[7] = (__bf16)b.w;
    return r;
}

// ---------------- fused main kernel ----------------------------------------
// Block: 512 threads = 8 waves, BN=128 rows.
// Phase A (per head): wave w -> rows 16w..16w+15.  A-frags of x from global
//   (fp32->bf16), B-frags of Wqkv^T from global (L1/L2 resident).
// Phase B: softmax over s=64 fully in-wave (row = 16-lane group x 4 regs).
// Phase C: out_slab[128x64] @ Wu_slab[64x512]; Wu slab staged to LDS per head;
//   wave tiles 4(M) x 8(N) of 16x16 for LDS-read reuse. acc persists 8 heads.
__global__ __launch_bounds__(512, 2) void fused_attn(
    const float* __restrict__ x,
    const __bf16* __restrict__ wqkv_t,
    const __bf16* __restrict__ wu_p,
    const float* __restrict__ bq, const float* __restrict__ bk,
    const float* __restrict__ bv, const float* __restrict__ bu,
    float* __restrict__ out)
{
    __shared__ __align__(16) __bf16 wu_s[512 * LDW];   // 90,112 B
    __shared__ __align__(16) __bf16 outs[BN * LDW];    // 22,528 B

    const int tid  = threadIdx.x;
    const int wave = tid >> 6;
    const int lane = tid & 63;
    const int g    = lane >> 4;     // 16-lane group (MFMA k-group / C row-group)
    const int l16  = lane & 15;
    const long n0  = (long)blockIdx.x * BN;

    const int mg = wave & 1;        // phase-C: rows 64*mg .. +63
    const int ng = wave >> 1;       // phase-C: cols 128*ng .. +127

    f32x4 acc[4][8];
    #pragma unroll
    for (int i = 0; i < 4; ++i)
        #pragma unroll
        for (int j = 0; j < 8; ++j)
            acc[i][j] = (f32x4){0.f, 0.f, 0.f, 0.f};

    const float* xrow = x + (n0 + 16 * wave + l16) * 512;

    for (int h = 0; h < 8; ++h) {
        // x A-fragments for this head: issue global loads before the barrier
        float4 xf0a = *(const float4*)(xrow + h * 64 +  0 + g * 8);
        float4 xf0b = *(const float4*)(xrow + h * 64 +  4 + g * 8);
        float4 xf1a = *(const float4*)(xrow + h * 64 + 32 + g * 8);
        float4 xf1b = *(const float4*)(xrow + h * 64 + 36 + g * 8);

        __syncthreads();   // previous head's phase C done with wu_s / outs

        // ---- stage Wu head-slab (64 KB) into LDS, padded rows ----
        {
            const uint4* src = (const uint4*)(wu_p + h * 32768);
            const int j = tid >> 3, c = tid & 7;
            #pragma unroll
            for (int p = 0; p < 8; ++p) {
                const int row = j + p * 64;
                uint4 v = src[row * 8 + c];
                *(uint4*)&wu_s[row * LDW + c * 8] = v;
            }
        }

        // ---- phase A: q,k,v for rows 16*wave..+15 ----
        bf16x8 afr[2];
        afr[0] = cvt8(xf0a, xf0b);
        afr[1] = cvt8(xf1a, xf1b);

        f32x4 qa[4], ka[4], va[4];
        #pragma unroll
        for (int nt = 0; nt < 4; ++nt) {
            qa[nt] = (f32x4){0.f, 0.f, 0.f, 0.f};
            ka[nt] = (f32x4){0.f, 0.f, 0.f, 0.f};
            va[nt] = (f32x4){0.f, 0.f, 0.f, 0.f};
        }
        #pragma unroll
        for (int nt = 0; nt < 4; ++nt) {
            const __bf16* wb = wqkv_t + (h * 192 + nt * 16 + l16) * 64 + g * 8;
            #pragma unroll
            for (int ks = 0; ks < 2; ++ks) {
                qa[nt] = MFMA16(afr[ks], *(const bf16x8*)(wb + ks * 32           ), qa[nt]);
                ka[nt] = MFMA16(afr[ks], *(const bf16x8*)(wb + ks * 32 +  64 * 64), ka[nt]);
                va[nt] = MFMA16(afr[ks], *(const bf16x8*)(wb + ks * 32 + 128 * 64), va[nt]);
            }
        }

        // ---- phase B: biases, softmax over the 64 head-dims, out = a*v ----
        float sum[4] = {0.f, 0.f, 0.f, 0.f};
        float ex[4][4];
        #pragma unroll
        for (int nt = 0; nt < 4; ++nt) {
            const int t = h * 64 + nt * 16 + l16;
            const float bq_ = bq[t], bk_ = bk[t], bv_ = bv[t];
            #pragma unroll
            for (int r = 0; r < 4; ++r) {
                const float qv = qa[nt][r] + bq_;
                const float kv = ka[nt][r] + bk_;
                va[nt][r] += bv_;
                const float e = __expf(qv * kv * QKSCALE);  // |logit|<~2: no max-sub needed
                ex[nt][r] = e;
                sum[r] += e;
            }
        }
        #pragma unroll
        for (int r = 0; r < 4; ++r) {           // row sum: reduce over 16-lane group
            float s = sum[r];
            s += __shfl_xor(s, 1);
            s += __shfl_xor(s, 2);
            s += __shfl_xor(s, 4);
            s += __shfl_xor(s, 8);
            sum[r] = 1.f / s;
        }
        #pragma unroll
        for (int nt = 0; nt < 4; ++nt)
            #pragma unroll
            for (int r = 0; r < 4; ++r) {
                const float o = ex[nt][r] * sum[r] * va[nt][r];
                outs[(16 * wave + 4 * g + r) * LDW + nt * 16 + l16] = (__bf16)o;
            }

        __syncthreads();   // outs + wu_s ready for all waves

        // ---- phase C: acc += out_slab @ Wu_slab ----
        #pragma unroll
        for (int ks = 0; ks < 2; ++ks) {
            bf16x8 afc[4], bfc[8];
            #pragma unroll
            for (int m = 0; m < 4; ++m)
                afc[m] = *(const bf16x8*)&outs[(mg * 64 + m * 16 + l16) * LDW + ks * 32 + g * 8];
            #pragma unroll
            for (int n = 0; n < 8; ++n)
                bfc[n] = *(const bf16x8*)&wu_s[(ng * 128 + n * 16 + l16) * LDW + ks * 32 + g * 8];
            #pragma unroll
            for (int m = 0; m < 4; ++m)
                #pragma unroll
                for (int n = 0; n < 8; ++n)
                    acc[m][n] = MFMA16(afc[m], bfc[n], acc[m][n]);
        }
    }

    // ---- epilogue: + bu, store fp32 ----
    #pragma unroll
    for (int n = 0; n < 8; ++n) {
        const int col = ng * 128 + n * 16 + l16;
        const float bu_ = bu[col];
        #pragma unroll
        for (int m = 0; m < 4; ++m) {
            const long rowbase = (n0 + mg * 64 + m * 16 + 4 * g) * 512;
            #pragma unroll
            for (int r = 0; r < 4; ++r)
                out[rowbase + (long)r * 512 + col] = acc[m][n][r] + bu_;
        }
    }
}

// ---------------------------------------------------------------------------
extern "C" void kernel_launch(void* const* d_in, const int* in_sizes, int n_in,
                              void* d_out, int out_size, void* d_ws, size_t ws_size,
                              hipStream_t stream)
{
    const float* x  = (const float*)d_in[0];
    const float* Wq = (const float*)d_in[1];
    const float* bq = (const float*)d_in[2];
    const float* Wk = (const float*)d_in[3];
    const float* bk = (const float*)d_in[4];
    const float* Wv = (const float*)d_in[5];
    const float* bv = (const float*)d_in[6];
    const float* Wu = (const float*)d_in[7];
    const float* bu = (const float*)d_in[8];
    float* out = (float*)d_out;

    __bf16* wu_p   = (__bf16*)d_ws;                          // 524,288 B
    __bf16* wqkv_t = (__bf16*)((char*)d_ws + 512 * 512 * 2); // 196,608 B

    // (262144 + 98304) / 512 = 704 blocks exactly
    prep_weights<<<704, 512, 0, stream>>>(Wq, Wk, Wv, Wu, wu_p, wqkv_t);
    fused_attn<<<NPTS / BN, 512, 0, stream>>>(x, wqkv_t, wu_p, bq, bk, bv, bu, out);
}

// Round 2
// 706.123 us; speedup vs baseline: 1.0420x; 1.0420x over previous
//
#include <hip/hip_runtime.h>

// ---------------------------------------------------------------------------
// SparseAttention on MI355X.  N=131072, e=512, h=8, s=64.
//
// R2 structure: two streaming kernels (the R1 fused design is latency-bound at
// 2 waves/SIMD because full-N fusion forces a 128-reg accumulator):
//   prep_split : Wq/Wk/Wv -> bf16 wqkv_t [h][192][64];  Wu -> bf16 Wu^T [512][512]
//   attn_kernel: per-wave QKV (MFMA 16x16x32) + softmax, NO block barriers,
//                wave-private LDS transpose, writes attn bf16 [N][512] to ws
//   gemm_kernel: attn[N,512] @ Wu^T + bu -> fp32 out, m97-style 128x128/BK=64,
//                global_load_lds(16B) staging, grid (4,1024) for A-tile L2 reuse
// Fallback: if ws_size < 135 MB, run the validated R1 fused path.
// ---------------------------------------------------------------------------

typedef __bf16 bf16x8 __attribute__((ext_vector_type(8)));
typedef float  f32x4  __attribute__((ext_vector_type(4)));

#define MFMA16(A, B, C) __builtin_amdgcn_mfma_f32_16x16x32_bf16((A), (B), (C), 0, 0, 0)

#define NPTS  131072
#define QKSCALE 0.044194173824159216f   // 1/sqrt(512)

__device__ __forceinline__ bf16x8 cvt8(float4 a, float4 b)
{
    bf16x8 r;
    r[0] = (__bf16)a.x; r[1] = (__bf16)a.y; r[2] = (__bf16)a.z; r[3] = (__bf16)a.w;
    r[4] = (__bf16)b.x; r[5] = (__bf16)b.y; r[6] = (__bf16)b.z; r[7] = (__bf16)b.w;
    return r;
}

__device__ __forceinline__ void gload_lds16(const void* g, void* lds)
{
    __builtin_amdgcn_global_load_lds(
        (const __attribute__((address_space(1))) unsigned int*)g,
        (__attribute__((address_space(3))) unsigned int*)lds, 16, 0, 0);
}

// ======================== split path ========================================

// wqkv_t[h][row=192][s=64]: rows 0..63 = Wq^T, 64..127 = Wk^T, 128..191 = Wv^T
// wu_t  [n=512][k=512]    = Wu[k][n]
__global__ void prep_split(const float* __restrict__ Wq, const float* __restrict__ Wk,
                           const float* __restrict__ Wv, const float* __restrict__ Wu,
                           __bf16* __restrict__ wqkv_t, __bf16* __restrict__ wu_t)
{
    int idx = blockIdx.x * 256 + threadIdx.x;
    if (idx < 512 * 512) {
        int n = idx >> 9, k = idx & 511;
        wu_t[idx] = (__bf16)Wu[k * 512 + n];
    } else {
        int o = idx - 512 * 512;
        if (o < 8 * 192 * 64) {
            int s    = o & 63;
            int row  = (o >> 6) % 192;
            int hh   = (o >> 6) / 192;
            int type = row >> 6;
            int t    = row & 63;
            const float* W = (type == 0) ? Wq : (type == 1) ? Wk : Wv;
            wqkv_t[o] = (__bf16)W[hh * 4096 + s * 64 + t];
        }
    }
}

// ---- attention kernel: one wave = 16 rows, no block barriers ---------------
#define ALD 72   // wave-private slab leading dim (bf16): 144B rows, ~2-way banks
__global__ __launch_bounds__(256, 4) void attn_kernel(
    const float* __restrict__ x,
    const __bf16* __restrict__ wqkv_t,
    const float* __restrict__ bq, const float* __restrict__ bk,
    const float* __restrict__ bv,
    __bf16* __restrict__ attn)
{
    __shared__ __align__(16) __bf16 slab[4][16 * ALD];   // 9216 B total

    const int tid  = threadIdx.x;
    const int wave = tid >> 6;
    const int lane = tid & 63;
    const int g    = lane >> 4;
    const int l16  = lane & 15;
    const long row0 = (long)blockIdx.x * 64 + wave * 16;

    const float* xrow = x + (row0 + l16) * 512;
    __bf16* wslab = &slab[wave][0];

    // prefetch head 0's x fragments
    float4 xa = *(const float4*)(xrow +  0 + g * 8);
    float4 xb = *(const float4*)(xrow +  4 + g * 8);
    float4 xc = *(const float4*)(xrow + 32 + g * 8);
    float4 xd = *(const float4*)(xrow + 36 + g * 8);

    for (int h = 0; h < 8; ++h) {
        bf16x8 a0 = cvt8(xa, xb);
        bf16x8 a1 = cvt8(xc, xd);
        if (h < 7) {   // prefetch next head while this head computes
            const float* xn = xrow + (h + 1) * 64;
            xa = *(const float4*)(xn +  0 + g * 8);
            xb = *(const float4*)(xn +  4 + g * 8);
            xc = *(const float4*)(xn + 32 + g * 8);
            xd = *(const float4*)(xn + 36 + g * 8);
        }

        f32x4 qa[4], ka[4], va[4];
        #pragma unroll
        for (int nt = 0; nt < 4; ++nt) {
            qa[nt] = (f32x4){0.f, 0.f, 0.f, 0.f};
            ka[nt] = (f32x4){0.f, 0.f, 0.f, 0.f};
            va[nt] = (f32x4){0.f, 0.f, 0.f, 0.f};
        }
        #pragma unroll
        for (int nt = 0; nt < 4; ++nt) {
            const __bf16* wb = wqkv_t + (h * 192 + nt * 16 + l16) * 64 + g * 8;
            #pragma unroll
            for (int ks = 0; ks < 2; ++ks) {
                const bf16x8 af = ks ? a1 : a0;
                qa[nt] = MFMA16(af, *(const bf16x8*)(wb + ks * 32           ), qa[nt]);
                ka[nt] = MFMA16(af, *(const bf16x8*)(wb + ks * 32 +  64 * 64), ka[nt]);
                va[nt] = MFMA16(af, *(const bf16x8*)(wb + ks * 32 + 128 * 64), va[nt]);
            }
        }

        // softmax over the 64 head-dims; row r lives in a 16-lane group
        float sum[4] = {0.f, 0.f, 0.f, 0.f};
        float ex[4][4];
        #pragma unroll
        for (int nt = 0; nt < 4; ++nt) {
            const int t = h * 64 + nt * 16 + l16;
            const float bq_ = bq[t], bk_ = bk[t], bv_ = bv[t];
            #pragma unroll
            for (int r = 0; r < 4; ++r) {
                const float qv = qa[nt][r] + bq_;
                const float kv = ka[nt][r] + bk_;
                va[nt][r] += bv_;
                const float e = __expf(qv * kv * QKSCALE);  // |logit| < ~2
                ex[nt][r] = e;
                sum[r] += e;
            }
        }
        #pragma unroll
        for (int r = 0; r < 4; ++r) {
            float s = sum[r];
            s += __shfl_xor(s, 1);
            s += __shfl_xor(s, 2);
            s += __shfl_xor(s, 4);
            s += __shfl_xor(s, 8);
            sum[r] = 1.f / s;
        }

        // wave-private transpose: C-layout (row=4g+r, col=nt*16+l16) -> row-major
        #pragma unroll
        for (int nt = 0; nt < 4; ++nt)
            #pragma unroll
            for (int r = 0; r < 4; ++r)
                wslab[(4 * g + r) * ALD + nt * 16 + l16] =
                    (__bf16)(ex[nt][r] * sum[r] * va[nt][r]);

        __builtin_amdgcn_s_waitcnt(0xc07f);   // lgkmcnt(0) only; keep vm prefetch alive

        // read back row-major, store 128B-coalesced: 2 rounds x (8 rows x 128B)
        #pragma unroll
        for (int p = 0; p < 2; ++p) {
            const int row = p * 8 + (lane >> 3);
            const int c   = lane & 7;
            uint4 v = *(const uint4*)&wslab[row * ALD + c * 8];
            *(uint4*)&attn[(row0 + row) * 512 + h * 64 + c * 8] = v;
        }
    }
}

// ---- GEMM kernel: out[N,512] = attn @ Wu^T + bu ----------------------------
#define BM 128
#define BNC 128
#define BK 64
__global__ __launch_bounds__(256, 3) void gemm_kernel(
    const __bf16* __restrict__ attn,
    const __bf16* __restrict__ wu_t,
    const float* __restrict__ bu,
    float* __restrict__ out)
{
    __shared__ __align__(16) __bf16 As[BM * BK];    // 16 KB, [row][k]
    __shared__ __align__(16) __bf16 Bs[BNC * BK];   // 16 KB, [n][k]

    const int tid  = threadIdx.x;
    const int wave = tid >> 6;
    const int lane = tid & 63;
    const int g    = lane >> 4;
    const int l16  = lane & 15;
    const int mw   = wave & 1;
    const int nw   = wave >> 1;

    const long m0 = (long)blockIdx.y * BM;
    const int  n0 = blockIdx.x * BNC;

    f32x4 acc[4][4];
    #pragma unroll
    for (int m = 0; m < 4; ++m)
        #pragma unroll
        for (int n = 0; n < 4; ++n)
            acc[m][n] = (f32x4){0.f, 0.f, 0.f, 0.f};

    const int srow  = tid >> 3;       // 0..31
    const int schnk = tid & 7;        // 0..7

    for (int k0 = 0; k0 < 512; k0 += BK) {
        __syncthreads();   // prior iteration's LDS reads done
        #pragma unroll
        for (int p = 0; p < 4; ++p) {
            const int row = p * 32 + srow;
            gload_lds16(attn + (m0 + row) * 512 + k0 + schnk * 8,
                        (char*)As + p * 4096 + tid * 16);
            gload_lds16(wu_t + (long)(n0 + row) * 512 + k0 + schnk * 8,
                        (char*)Bs + p * 4096 + tid * 16);
        }
        __syncthreads();   // staging complete (vmcnt(0) drained by barrier)

        #pragma unroll
        for (int ks = 0; ks < 2; ++ks) {
            bf16x8 af[4], bf[4];
            #pragma unroll
            for (int m = 0; m < 4; ++m)
                af[m] = *(const bf16x8*)&As[(mw * 64 + m * 16 + l16) * BK + ks * 32 + g * 8];
            #pragma unroll
            for (int n = 0; n < 4; ++n)
                bf[n] = *(const bf16x8*)&Bs[(nw * 64 + n * 16 + l16) * BK + ks * 32 + g * 8];
            #pragma unroll
            for (int m = 0; m < 4; ++m)
                #pragma unroll
                for (int n = 0; n < 4; ++n)
                    acc[m][n] = MFMA16(af[m], bf[n], acc[m][n]);
        }
    }

    // epilogue: + bu, fp32 store
    #pragma unroll
    for (int n = 0; n < 4; ++n) {
        const int col = n0 + nw * 64 + n * 16 + l16;
        const float bu_ = bu[col];
        #pragma unroll
        for (int m = 0; m < 4; ++m) {
            const long rowb = m0 + mw * 64 + m * 16 + 4 * g;
            #pragma unroll
            for (int r = 0; r < 4; ++r)
                out[(rowb + r) * 512 + col] = acc[m][n][r] + bu_;
        }
    }
}

// ======================== fallback: validated R1 fused path =================

#define BN    128
#define LDW   88

__global__ void prep_weights(const float* __restrict__ Wq, const float* __restrict__ Wk,
                             const float* __restrict__ Wv, const float* __restrict__ Wu,
                             __bf16* __restrict__ wu_p, __bf16* __restrict__ wqkv_t)
{
    int idx = blockIdx.x * 512 + threadIdx.x;
    if (idx < 512 * 512) {
        int kk = idx & 63;
        int j  = (idx >> 6) & 511;
        int h  = idx >> 15;
        wu_p[idx] = (__bf16)Wu[(h * 64 + kk) * 512 + j];
    } else {
        int o = idx - 512 * 512;
        if (o < 8 * 192 * 64) {
            int s    = o & 63;
            int row  = (o >> 6) % 192;
            int h    = (o >> 6) / 192;
            int type = row >> 6;
            int t    = row & 63;
            const float* W = (type == 0) ? Wq : (type == 1) ? Wk : Wv;
            wqkv_t[o] = (__bf16)W[h * 4096 + s * 64 + t];
        }
    }
}

__global__ __launch_bounds__(512, 2) void fused_attn(
    const float* __restrict__ x,
    const __bf16* __restrict__ wqkv_t,
    const __bf16* __restrict__ wu_p,
    const float* __restrict__ bq, const float* __restrict__ bk,
    const float* __restrict__ bv, const float* __restrict__ bu,
    float* __restrict__ out)
{
    __shared__ __align__(16) __bf16 wu_s[512 * LDW];
    __shared__ __align__(16) __bf16 outs[BN * LDW];

    const int tid  = threadIdx.x;
    const int wave = tid >> 6;
    const int lane = tid & 63;
    const int g    = lane >> 4;
    const int l16  = lane & 15;
    const long n0  = (long)blockIdx.x * BN;

    const int mg = wave & 1;
    const int ng = wave >> 1;

    f32x4 acc[4][8];
    #pragma unroll
    for (int i = 0; i < 4; ++i)
        #pragma unroll
        for (int j = 0; j < 8; ++j)
            acc[i][j] = (f32x4){0.f, 0.f, 0.f, 0.f};

    const float* xrow = x + (n0 + 16 * wave + l16) * 512;

    for (int h = 0; h < 8; ++h) {
        float4 xf0a = *(const float4*)(xrow + h * 64 +  0 + g * 8);
        float4 xf0b = *(const float4*)(xrow + h * 64 +  4 + g * 8);
        float4 xf1a = *(const float4*)(xrow + h * 64 + 32 + g * 8);
        float4 xf1b = *(const float4*)(xrow + h * 64 + 36 + g * 8);

        __syncthreads();

        {
            const uint4* src = (const uint4*)(wu_p + h * 32768);
            const int j = tid >> 3, c = tid & 7;
            #pragma unroll
            for (int p = 0; p < 8; ++p) {
                const int row = j + p * 64;
                uint4 v = src[row * 8 + c];
                *(uint4*)&wu_s[row * LDW + c * 8] = v;
            }
        }

        bf16x8 afr[2];
        afr[0] = cvt8(xf0a, xf0b);
        afr[1] = cvt8(xf1a, xf1b);

        f32x4 qa[4], ka[4], va[4];
        #pragma unroll
        for (int nt = 0; nt < 4; ++nt) {
            qa[nt] = (f32x4){0.f, 0.f, 0.f, 0.f};
            ka[nt] = (f32x4){0.f, 0.f, 0.f, 0.f};
            va[nt] = (f32x4){0.f, 0.f, 0.f, 0.f};
        }
        #pragma unroll
        for (int nt = 0; nt < 4; ++nt) {
            const __bf16* wb = wqkv_t + (h * 192 + nt * 16 + l16) * 64 + g * 8;
            #pragma unroll
            for (int ks = 0; ks < 2; ++ks) {
                qa[nt] = MFMA16(afr[ks], *(const bf16x8*)(wb + ks * 32           ), qa[nt]);
                ka[nt] = MFMA16(afr[ks], *(const bf16x8*)(wb + ks * 32 +  64 * 64), ka[nt]);
                va[nt] = MFMA16(afr[ks], *(const bf16x8*)(wb + ks * 32 + 128 * 64), va[nt]);
            }
        }

        float sum[4] = {0.f, 0.f, 0.f, 0.f};
        float ex[4][4];
        #pragma unroll
        for (int nt = 0; nt < 4; ++nt) {
            const int t = h * 64 + nt * 16 + l16;
            const float bq_ = bq[t], bk_ = bk[t], bv_ = bv[t];
            #pragma unroll
            for (int r = 0; r < 4; ++r) {
                const float qv = qa[nt][r] + bq_;
                const float kv = ka[nt][r] + bk_;
                va[nt][r] += bv_;
                const float e = __expf(qv * kv * QKSCALE);
                ex[nt][r] = e;
                sum[r] += e;
            }
        }
        #pragma unroll
        for (int r = 0; r < 4; ++r) {
            float s = sum[r];
            s += __shfl_xor(s, 1);
            s += __shfl_xor(s, 2);
            s += __shfl_xor(s, 4);
            s += __shfl_xor(s, 8);
            sum[r] = 1.f / s;
        }
        #pragma unroll
        for (int nt = 0; nt < 4; ++nt)
            #pragma unroll
            for (int r = 0; r < 4; ++r) {
                const float o = ex[nt][r] * sum[r] * va[nt][r];
                outs[(16 * wave + 4 * g + r) * LDW + nt * 16 + l16] = (__bf16)o;
            }

        __syncthreads();

        #pragma unroll
        for (int ks = 0; ks < 2; ++ks) {
            bf16x8 afc[4], bfc[8];
            #pragma unroll
            for (int m = 0; m < 4; ++m)
                afc[m] = *(const bf16x8*)&outs[(mg * 64 + m * 16 + l16) * LDW + ks * 32 + g * 8];
            #pragma unroll
            for (int n = 0; n < 8; ++n)
                bfc[n] = *(const bf16x8*)&wu_s[(ng * 128 + n * 16 + l16) * LDW + ks * 32 + g * 8];
            #pragma unroll
            for (int m = 0; m < 4; ++m)
                #pragma unroll
                for (int n = 0; n < 8; ++n)
                    acc[m][n] = MFMA16(afc[m], bfc[n], acc[m][n]);
        }
    }

    #pragma unroll
    for (int n = 0; n < 8; ++n) {
        const int col = ng * 128 + n * 16 + l16;
        const float bu_ = bu[col];
        #pragma unroll
        for (int m = 0; m < 4; ++m) {
            const long rowbase = (n0 + mg * 64 + m * 16 + 4 * g) * 512;
            #pragma unroll
            for (int r = 0; r < 4; ++r)
                out[rowbase + (long)r * 512 + col] = acc[m][n][r] + bu_;
        }
    }
}

// ---------------------------------------------------------------------------
extern "C" void kernel_launch(void* const* d_in, const int* in_sizes, int n_in,
                              void* d_out, int out_size, void* d_ws, size_t ws_size,
                              hipStream_t stream)
{
    const float* x  = (const float*)d_in[0];
    const float* Wq = (const float*)d_in[1];
    const float* bq = (const float*)d_in[2];
    const float* Wk = (const float*)d_in[3];
    const float* bk = (const float*)d_in[4];
    const float* Wv = (const float*)d_in[5];
    const float* bv = (const float*)d_in[6];
    const float* Wu = (const float*)d_in[7];
    const float* bu = (const float*)d_in[8];
    float* out = (float*)d_out;

    const size_t attn_bytes = (size_t)NPTS * 512 * 2;           // 134,217,728
    const size_t need = attn_bytes + 196608 + 524288;           // 134,938,624

    if (ws_size >= need) {
        __bf16* attn   = (__bf16*)d_ws;
        __bf16* wqkv_t = (__bf16*)((char*)d_ws + attn_bytes);
        __bf16* wu_t   = (__bf16*)((char*)d_ws + attn_bytes + 196608);

        // (262144 + 98304) / 256 = 1408 blocks exactly
        prep_split<<<1408, 256, 0, stream>>>(Wq, Wk, Wv, Wu, wqkv_t, wu_t);
        attn_kernel<<<NPTS / 64, 256, 0, stream>>>(x, wqkv_t, bq, bk, bv, attn);
        gemm_kernel<<<dim3(4, NPTS / BM), 256, 0, stream>>>(attn, wu_t, bu, out);
    } else {
        __bf16* wu_p   = (__bf16*)d_ws;
        __bf16* wqkv_t = (__bf16*)((char*)d_ws + 512 * 512 * 2);
        prep_weights<<<704, 512, 0, stream>>>(Wq, Wk, Wv, Wu, wu_p, wqkv_t);
        fused_attn<<<NPTS / BN, 512, 0, stream>>>(x, wqkv_t, wu_p, bq, bk, bv, bu, out);
    }
}